// Round 8
// baseline (255.252 us; speedup 1.0000x reference)
//
#include <hip/hip_runtime.h>
#include <hip/hip_bf16.h>

#define N_NODES 50000
#define E_EDGES 800000
#define IN_F    128
#define OUT_F   64
#define HEADS   4
#define HF      (HEADS * OUT_F)   // 256
#define NEG_SLOPE 0.2f
#define EPS     1e-8f
#define NB_SCAN ((N_NODES + 255) / 256)   // 196 scan blocks
#define NPB     64                        // nodes per proj block
#define PROJ_BLOCKS ((N_NODES + NPB - 1) / NPB)   // 782

typedef __attribute__((ext_vector_type(8))) short bf16x8;
typedef __attribute__((ext_vector_type(8))) unsigned short u16x8;
typedef __attribute__((ext_vector_type(4))) float f32x4;

__device__ __forceinline__ unsigned short f2bf(float f) {
    return __hip_bfloat16_raw(__float2bfloat16(f)).x;
}
__device__ __forceinline__ float bf2f(unsigned short u) {
    return __uint_as_float((unsigned)u << 16);
}

// ---------------- Kernel 0: W->bf16 transposed, wa = W@a, cursor zero -------
__global__ __launch_bounds__(256) void wcvt_kernel(
    const float* __restrict__ W,      // [H][IN_F][OUT_F]
    const float* __restrict__ a_src,  // [H][OUT_F]
    const float* __restrict__ a_dst,  // [H][OUT_F]
    short* __restrict__ Wtb,          // [H][OUT_F][IN_F] bf16 bits
    float* __restrict__ wa,           // [2][H][IN_F] fp32 (0=src, 1=dst)
    int* __restrict__ cursor)         // [N] -> 0
{
    const int i = blockIdx.x * 256 + threadIdx.x;   // 196*256 = 50176
    if (i < N_NODES) cursor[i] = 0;
    if (i < HEADS * IN_F * OUT_F) {
        const int h  = i >> 13;
        const int fl = (i >> 7) & 63;
        const int k  = i & 127;
        Wtb[i] = (short)f2bf(W[h * (IN_F * OUT_F) + k * OUT_F + fl]);
    }
    if (i < 2 * HEADS * IN_F) {       // 1024 dot products of length 64
        const int pair = i >> 9;
        const int h = (i >> 7) & 3;
        const int k = i & 127;
        const float* av = (pair ? a_dst : a_src) + h * OUT_F;
        const float* wrow = W + h * (IN_F * OUT_F) + k * OUT_F;
        float s = 0.f;
        for (int f = 0; f < OUT_F; ++f) s += wrow[f] * av[f];
        wa[i] = s;
    }
}

// ---------------- Kernel 1: MFMA projection (64 nodes/block) ----------------
// 4 waves; wave w = head w. B-fragments (16 KB/head) loaded ONCE into VGPRs,
// reused across 4 M-tiles of 16 nodes. Logits = one extra MFMA vs [wa_src|wa_dst].
__global__ __launch_bounds__(256) void proj_kernel(
    const float* __restrict__ x,      // [N][IN_F]
    const short* __restrict__ Wtb,    // [H][OUT_F][IN_F] bf16
    const float* __restrict__ wa,     // [2][H][IN_F]
    const int* __restrict__ dst,      // [E]
    unsigned short* __restrict__ Whb, // [N][OUT_F*HEADS] bf16 ([n][f*4+h])
    float* __restrict__ esrc,         // [N][H]
    float* __restrict__ edst,         // [N][H]
    int* __restrict__ cnt)            // [N], zeroed by wcvt
{
    __shared__ short xs[NPB][136];            // 17.4 KB bf16 x tile
    __shared__ unsigned short ot[NPB][264];   // 33.8 KB transpose buf (padded)

    const int tid = threadIdx.x;
    const int n0 = blockIdx.x * NPB;

    // fused degree count: 782 blocks * 1024 >= 800000
#pragma unroll
    for (int i = 0; i < 4; ++i) {
        const int e = blockIdx.x * 1024 + i * 256 + tid;
        if (e < E_EDGES) atomicAdd(&cnt[dst[e]], 1);
    }

    // stage x -> bf16 LDS: thread t: row t>>2, k0 = (t&3)*32
    {
        const int row = tid >> 2;
        const int k0 = (tid & 3) * 32;
        if (n0 + row < N_NODES) {
            const float* xp = x + (size_t)(n0 + row) * IN_F + k0;
#pragma unroll
            for (int u = 0; u < 4; ++u) {
                const float4 v0 = *(const float4*)(xp + u * 8);
                const float4 v1 = *(const float4*)(xp + u * 8 + 4);
                bf16x8 v;
                v[0] = (short)f2bf(v0.x); v[1] = (short)f2bf(v0.y);
                v[2] = (short)f2bf(v0.z); v[3] = (short)f2bf(v0.w);
                v[4] = (short)f2bf(v1.x); v[5] = (short)f2bf(v1.y);
                v[6] = (short)f2bf(v1.z); v[7] = (short)f2bf(v1.w);
                *(bf16x8*)&xs[row][k0 + u * 8] = v;
            }
        } else {
            const bf16x8 z = (bf16x8){0,0,0,0,0,0,0,0};
#pragma unroll
            for (int u = 0; u < 4; ++u) *(bf16x8*)&xs[row][k0 + u * 8] = z;
        }
    }

    const int h = tid >> 6;
    const int lane = tid & 63;
    const int c = lane & 15;
    const int quad = lane >> 4;

    // B fragments, held in VGPRs for all 4 M-tiles
    bf16x8 b[4][4];
    const short* Wh_head = Wtb + (h << 13);
#pragma unroll
    for (int nt = 0; nt < 4; ++nt) {
        const short* wrow = Wh_head + ((nt * 16 + c) << 7) + (quad << 3);
#pragma unroll
        for (int ks = 0; ks < 4; ++ks)
            b[nt][ks] = *(const bf16x8*)(wrow + (ks << 5));
    }

    // logit B-fragment: col 0 = wa_src, col 1 = wa_dst, cols 2..15 = 0
    bf16x8 be[4];
    {
        const float* wp = wa + (c == 1 ? HEADS * IN_F : 0) + h * IN_F + (quad << 3);
#pragma unroll
        for (int ks = 0; ks < 4; ++ks) {
            bf16x8 v;
#pragma unroll
            for (int j = 0; j < 8; ++j)
                v[j] = (c < 2) ? (short)f2bf(wp[ks * 32 + j]) : (short)0;
            be[ks] = v;
        }
    }
    __syncthreads();

#pragma unroll
    for (int mt = 0; mt < 4; ++mt) {
        bf16x8 a[4];
#pragma unroll
        for (int ks = 0; ks < 4; ++ks)
            a[ks] = *(const bf16x8*)&xs[mt * 16 + c][ks * 32 + (quad << 3)];

        f32x4 acc[4];
#pragma unroll
        for (int nt = 0; nt < 4; ++nt) acc[nt] = (f32x4){0.f, 0.f, 0.f, 0.f};
#pragma unroll
        for (int nt = 0; nt < 4; ++nt)
#pragma unroll
            for (int ks = 0; ks < 4; ++ks)
                acc[nt] = __builtin_amdgcn_mfma_f32_16x16x32_bf16(a[ks], b[nt][ks], acc[nt], 0, 0, 0);

        // logits via MFMA: C[row=node][col0]=e_src, [col1]=e_dst
        f32x4 acce = (f32x4){0.f, 0.f, 0.f, 0.f};
#pragma unroll
        for (int ks = 0; ks < 4; ++ks)
            acce = __builtin_amdgcn_mfma_f32_16x16x32_bf16(a[ks], be[ks], acce, 0, 0, 0);
        if (c < 2) {
            float* p = (c == 0) ? esrc : edst;
#pragma unroll
            for (int r = 0; r < 4; ++r) {
                const int nn = n0 + mt * 16 + quad * 4 + r;
                if (nn < N_NODES) p[nn * HEADS + h] = acce[r];
            }
        }

        // transpose into ot (rows mt*16 .. mt*16+15; disjoint across mt)
#pragma unroll
        for (int nt = 0; nt < 4; ++nt)
#pragma unroll
            for (int r = 0; r < 4; ++r)
                ot[mt * 16 + quad * 4 + r][(nt * 16 + c) * 4 + h] = f2bf(acc[nt][r]);
    }

    __syncthreads();
    // bulk coalesced store: 64 rows x 256 cols bf16
#pragma unroll
    for (int u = 0; u < 4; ++u) {
        const int idx = u * 256 + tid;          // 1024 chunks of 16 ushorts
        const int row = idx >> 4;
        if (n0 + row < N_NODES) {
            const unsigned short* sp2 = &ot[row][(idx & 15) * 16];
            unsigned short* gp = Whb + (size_t)n0 * HF + idx * 16;
            *(int4*)gp = *(const int4*)sp2;
            *(int4*)(gp + 8) = *(const int4*)(sp2 + 8);
        }
    }
}

// ---------------- Scan phase 1: per-block exclusive scan --------------------
__global__ __launch_bounds__(256) void scan1_kernel(
    int* __restrict__ cursor, int* __restrict__ bsum)
{
    __shared__ int ws[4];
    const int tid = threadIdx.x;
    const int lane = tid & 63;
    const int wid = tid >> 6;
    const int i = blockIdx.x * 256 + tid;
    const int v = (i < N_NODES) ? cursor[i] : 0;
    int xv = v;
#pragma unroll
    for (int off = 1; off < 64; off <<= 1) {
        int y = __shfl_up(xv, off);
        if (lane >= off) xv += y;
    }
    if (lane == 63) ws[wid] = xv;
    __syncthreads();
    int wo = 0;
    if (wid > 0) wo += ws[0];
    if (wid > 1) wo += ws[1];
    if (wid > 2) wo += ws[2];
    const int excl = xv - v + wo;
    if (i < N_NODES) cursor[i] = excl;
    if (tid == 255) bsum[blockIdx.x] = excl + v;
}

// ---------------- Scan phase 2+3 merged -------------------------------------
__global__ __launch_bounds__(256) void scan23_kernel(
    int* __restrict__ cursor, int* __restrict__ offs,
    const int* __restrict__ bsum)
{
    __shared__ int wsum[4];
    const int t = threadIdx.x;
    int v = (t < blockIdx.x) ? bsum[t] : 0;
#pragma unroll
    for (int m = 1; m < 64; m <<= 1) v += __shfl_xor(v, m);
    if ((t & 63) == 0) wsum[t >> 6] = v;
    __syncthreads();
    const int pref = wsum[0] + wsum[1] + wsum[2] + wsum[3];
    const int i = blockIdx.x * 256 + t;
    if (i < N_NODES) {
        const int val = cursor[i] + pref;
        cursor[i] = val;
        offs[i] = val;
    }
    if (i == 0) offs[N_NODES] = E_EDGES;
}

// ---------------- Kernel 2: CSR scatter -------------------------------------
__global__ __launch_bounds__(256) void scatter_kernel(
    const int* __restrict__ src,
    const int* __restrict__ dst,
    int* __restrict__ cursor,         // consumed
    int* __restrict__ csr_src)        // [E] src node ids grouped by dst
{
    const int e = blockIdx.x * 256 + threadIdx.x;
    if (e >= E_EDGES) return;
    const int pos = atomicAdd(&cursor[dst[e]], 1);
    csr_src[pos] = src[e];
}

// ---------------- Kernel 3: fused softmax + aggregation ---------------------
// One wave per dst node, half-wave split: 32 lanes x 16B per edge row,
// 2 edges per step + pair unroll (4 gathers in flight). LDS wave-synchronous.
// o[j] accumulates Whb col li*8+j = (f = li*2+(j>>2), h = j&3); epilogue
// de-interleaves into out[d][h*64+f].
__global__ __launch_bounds__(256) void aggregate_kernel(
    const int* __restrict__ offs,     // [N+1]
    const int* __restrict__ csr_src,  // [E]
    const float* __restrict__ esrc,   // [N][H]
    const float* __restrict__ edst,   // [N][H]
    const unsigned short* __restrict__ Whb, // [N][OUT_F*HEADS] bf16
    float* __restrict__ out)          // [N][H*OUT_F]
{
    __shared__ int   sb[4][64];
    __shared__ float pb[4][64][4];

    const int wid = threadIdx.x >> 6;
    const int lane = threadIdx.x & 63;
    const int d = blockIdx.x * 4 + wid;   // 12500*4 = 50000 exact

    const int rs = offs[d];
    const int re = offs[d + 1];
    const float4 ed4 = *(const float4*)(edst + d * HEADS);

    const int h2 = lane >> 5;             // half id: edge parity
    const int li = lane & 31;             // lane within half: col block
    const unsigned short* wbase = Whb + li * 8;   // cols 8li..8li+7

    float o[8];
#pragma unroll
    for (int j = 0; j < 8; ++j) o[j] = 0.f;
    float l0 = 0.f, l1 = 0.f, l2 = 0.f, l3 = 0.f;

    for (int base = rs; base < re; base += 64) {
        const int rem = re - base;
        const int cnt = rem < 64 ? rem : 64;
        if (lane < cnt) {
            const int s = csr_src[base + lane];
            const float4 es4 = *(const float4*)(esrc + s * HEADS);
            float v0 = es4.x + ed4.x; v0 = v0 > 0.f ? v0 : NEG_SLOPE * v0;
            float v1 = es4.y + ed4.y; v1 = v1 > 0.f ? v1 : NEG_SLOPE * v1;
            float v2 = es4.z + ed4.z; v2 = v2 > 0.f ? v2 : NEG_SLOPE * v2;
            float v3 = es4.w + ed4.w; v3 = v3 > 0.f ? v3 : NEG_SLOPE * v3;
            const float p0 = __expf(v0);
            const float p1 = __expf(v1);
            const float p2 = __expf(v2);
            const float p3 = __expf(v3);
            l0 += p0; l1 += p1; l2 += p2; l3 += p3;
            sb[wid][lane] = s;
            *(float4*)pb[wid][lane] = (float4){p0, p1, p2, p3};
        } else {
            sb[wid][lane] = 0;
            *(float4*)pb[wid][lane] = (float4){0.f, 0.f, 0.f, 0.f};
        }
        // wave-synchronous: same wave wrote sb/pb
        const int cnt4 = (cnt + 3) & ~3;
        for (int p = 0; p < cnt4; p += 4) {
            const int eA = p + h2;
            const int eB = p + 2 + h2;
            const int sA = sb[wid][eA];
            const int sB = sb[wid][eB];
            const float4 qA = *(const float4*)pb[wid][eA];
            const float4 qB = *(const float4*)pb[wid][eB];
            const u16x8 wA = *(const u16x8*)(wbase + (size_t)sA * HF);
            const u16x8 wB = *(const u16x8*)(wbase + (size_t)sB * HF);
            const float* qap = (const float*)&qA;
            const float* qbp = (const float*)&qB;
#pragma unroll
            for (int j = 0; j < 8; ++j) {
                o[j] += qap[j & 3] * bf2f(wA[j]);
                o[j] += qbp[j & 3] * bf2f(wB[j]);
            }
        }
    }

    // l: all-reduce across 64 lanes (each staged edge counted once)
#pragma unroll
    for (int m = 1; m < 64; m <<= 1) {
        l0 += __shfl_xor(l0, m);
        l1 += __shfl_xor(l1, m);
        l2 += __shfl_xor(l2, m);
        l3 += __shfl_xor(l3, m);
    }
    // merge the two halves' partial sums
#pragma unroll
    for (int j = 0; j < 8; ++j) o[j] += __shfl_xor(o[j], 32);

    if (h2 == 0) {
        const float r[4] = { 1.f / (l0 + EPS), 1.f / (l1 + EPS),
                             1.f / (l2 + EPS), 1.f / (l3 + EPS) };
        // de-interleave: j=hh -> (h=hh, f=li*2), j=hh+4 -> (h=hh, f=li*2+1)
#pragma unroll
        for (int hh = 0; hh < 4; ++hh) {
            float2 v;
            v.x = o[hh] * r[hh];
            v.y = o[hh + 4] * r[hh];
            *(float2*)(out + (size_t)d * HF + hh * OUT_F + li * 2) = v;
        }
    }
}

extern "C" void kernel_launch(void* const* d_in, const int* in_sizes, int n_in,
                              void* d_out, int out_size, void* d_ws, size_t ws_size,
                              hipStream_t stream) {
    const float* x      = (const float*)d_in[0];
    const int*   eidx   = (const int*)d_in[1];     // [2][E]
    const float* W      = (const float*)d_in[2];
    const float* a_src  = (const float*)d_in[3];
    const float* a_dst  = (const float*)d_in[4];
    float* out = (float*)d_out;

    const int* src = eidx;
    const int* dst = eidx + E_EDGES;

    // workspace layout
    unsigned short* Whb = (unsigned short*)d_ws;                  // N*HF bf16 (25.6 MB)
    float* esrc   = (float*)(Whb + (size_t)N_NODES * HF);         // N*H
    float* edst   = esrc + (size_t)N_NODES * HEADS;               // N*H
    int*   cursor = (int*)(edst + (size_t)N_NODES * HEADS);       // N
    int*   offs   = cursor + N_NODES;                             // N+1
    int*   bsum   = offs + N_NODES + 1;                           // 256
    int*   csr_src= bsum + 256;                                   // E
    short* Wtb    = (short*)(csr_src + E_EDGES);                  // H*OUT_F*IN_F bf16
    float* wa     = (float*)(Wtb + HEADS * OUT_F * IN_F);         // 2*H*IN_F fp32

    wcvt_kernel<<<NB_SCAN, 256, 0, stream>>>(W, a_src, a_dst, Wtb, wa, cursor);

    proj_kernel<<<PROJ_BLOCKS, 256, 0, stream>>>(x, Wtb, wa, dst,
                                                 Whb, esrc, edst, cursor);

    scan1_kernel<<<NB_SCAN, 256, 0, stream>>>(cursor, bsum);
    scan23_kernel<<<NB_SCAN, 256, 0, stream>>>(cursor, offs, bsum);

    const int eblocks = (E_EDGES + 255) / 256;
    scatter_kernel<<<eblocks, 256, 0, stream>>>(src, dst, cursor, csr_src);

    aggregate_kernel<<<N_NODES / 4, 256, 0, stream>>>(offs, csr_src, esrc, edst, Whb, out);
}